// Round 19
// baseline (427.996 us; speedup 1.0000x reference)
//
#include <hip/hip_runtime.h>
#include <cstddef>

// GCN encoder, BN-folded, split gather->GEMM (fusion net-negative r10/r11).
// Head: weight-stationary split-bf16 MFMA; r18 adds LDS output staging so
// stores are coalesced 512B rows (D-layout gives each lane 4 cols of ONE row
// -> raw stores were 16B x 64-lane scattered = write-amplified).
// prop(h)[d] = dinv[d]*(P(h)[d] @ W) + b; BN folded via W'=diag(sc)W, c'=sh@W,
// q[d] = sum dinv; epilogue u = dv*acc + dv*q[r]*c'[c] + b[c].

#define NEG_SLOPE 0.01f
#define BN_EPS 1e-5f

typedef unsigned short u16;
typedef __attribute__((ext_vector_type(8))) short bf16x8;
typedef __attribute__((ext_vector_type(4))) float f32x4;

__device__ __forceinline__ unsigned bf16_rne(float x) {
  unsigned u = __float_as_uint(x);
  return (u + 0x7fffu + ((u >> 16) & 1u)) >> 16;
}

__global__ __launch_bounds__(256) void init_k(int* __restrict__ cnt,
                                              float* __restrict__ bns, int N) {
  int i = blockIdx.x * 256 + threadIdx.x;
  if (i < N) cnt[i] = 0;
  if (i < 384) bns[i] = 0.0f;  // 3 layers x {sum[64], sumsq[64]}
}

__global__ __launch_bounds__(256) void hist_k(const int* __restrict__ dst,
                                              int* __restrict__ cnt, int E) {
  int e = blockIdx.x * 256 + threadIdx.x;
  if (e < E) atomicAdd(&cnt[dst[e]], 1);
}

__global__ __launch_bounds__(1024) void scanA(const int* __restrict__ cnt,
                                              int* __restrict__ pre,
                                              int* __restrict__ bsum, int N) {
  __shared__ int sh[1024];
  const int t = threadIdx.x;
  const int i = blockIdx.x * 1024 + t;
  int c = (i < N) ? cnt[i] : 0;
  sh[t] = c;
  __syncthreads();
  for (int off = 1; off < 1024; off <<= 1) {
    int v = (t >= off) ? sh[t - off] : 0;
    __syncthreads();
    sh[t] += v;
    __syncthreads();
  }
  if (i < N) pre[i] = sh[t] - c;  // exclusive
  if (t == 1023) bsum[blockIdx.x] = sh[t];
}

__global__ __launch_bounds__(64) void scanB(int* __restrict__ bsum, int nb) {
  int t = threadIdx.x;
  int orig = (t < nb) ? bsum[t] : 0;
  int v = orig;
#pragma unroll
  for (int off = 1; off < 64; off <<= 1) {
    int u = __shfl_up(v, off);
    if (t >= off) v += u;
  }
  if (t < nb) bsum[t] = v - orig;
}

// Phase C: rowptr/cursor finalize, dinv, and xd = {x*dinv, dinv} pack.
__global__ __launch_bounds__(256) void scanC(const int* __restrict__ cnt,
                                             int* __restrict__ rowptr,
                                             int* __restrict__ cursor,
                                             const int* __restrict__ bsum,
                                             const float* __restrict__ x,
                                             float* __restrict__ dinv,
                                             float4* __restrict__ xd,
                                             int N, int E) {
  int i = blockIdx.x * 256 + threadIdx.x;
  if (i < N) {
    int rp = rowptr[i] + bsum[i >> 10];
    rowptr[i] = rp;
    cursor[i] = rp;
    float dv = rsqrtf((float)(cnt[i] + 1));  // +1 self loop
    dinv[i] = dv;
    xd[i] = make_float4(x[i * 3] * dv, x[i * 3 + 1] * dv, x[i * 3 + 2] * dv, dv);
  }
  if (i == 0) rowptr[N] = E;
}

__global__ __launch_bounds__(256) void fill_k(const int* __restrict__ src,
                                              const int* __restrict__ dst,
                                              int* __restrict__ cursor,
                                              int* __restrict__ eidx, int E) {
  int e = blockIdx.x * 256 + threadIdx.x;
  if (e >= E) return;
  int p = atomicAdd(&cursor[dst[e]], 1);
  eidx[p] = src[e];
}

// Layer 1 fully fused (3ch gather via xd float4 + 3->64 matvec + stats + q).
__global__ __launch_bounds__(256) void l1_fused(
    const int* __restrict__ rowptr, const int* __restrict__ eidx,
    const float4* __restrict__ xd, const float* __restrict__ W1,
    const float* __restrict__ b1, float* __restrict__ Z, float* __restrict__ q,
    float* __restrict__ bns, int N) {
  const int t = threadIdx.x, lane = t & 63, wid = t >> 6;
  const int gw = blockIdx.x * 4 + wid;
  const int nw = gridDim.x * 4;
  const float w0 = W1[lane], w1 = W1[64 + lane], w2 = W1[128 + lane];
  const float bb = b1[lane];
  float s1 = 0.f, s2 = 0.f;
  for (int node = gw; node < N; node += nw) {
    int beg = rowptr[node], end = rowptr[node + 1];
    float a0 = 0.f, a1 = 0.f, a2 = 0.f, aq = 0.f;
    for (int e = beg + lane; e < end; e += 64) {
      float4 v = xd[eidx[e]];
      a0 += v.x;
      a1 += v.y;
      a2 += v.z;
      aq += v.w;
    }
#pragma unroll
    for (int off = 32; off; off >>= 1) {
      a0 += __shfl_xor(a0, off);
      a1 += __shfl_xor(a1, off);
      a2 += __shfl_xor(a2, off);
      aq += __shfl_xor(aq, off);
    }
    float4 sv = xd[node];
    float dv = sv.w;
    a0 += sv.x;
    a1 += sv.y;
    a2 += sv.z;
    aq += dv;
    float u = dv * (a0 * w0 + a1 * w1 + a2 * w2) + bb;
    float o = u >= 0.f ? u : NEG_SLOPE * u;
    Z[(size_t)node * 64 + lane] = o * dv;
    s1 += o;
    s2 += o * o;
    if (lane == 0) q[node] = aq;
  }
  __shared__ float red[8][64];
  red[wid][lane] = s1;
  red[4 + wid][lane] = s2;
  __syncthreads();
  if (t < 64) {
    atomicAdd(&bns[t], red[0][t] + red[1][t] + red[2][t] + red[3][t]);
    atomicAdd(&bns[64 + t], red[4][t] + red[5][t] + red[6][t] + red[7][t]);
  }
}

// Standalone gather, 4-deep ILP: G[node][c] = Z[node][c] + sum Z[src][c].
__global__ __launch_bounds__(256) void gather64(const int* __restrict__ rowptr,
                                                const int* __restrict__ eidx,
                                                const float* __restrict__ Z,
                                                float* __restrict__ G, int N) {
  int node = blockIdx.x * 4 + (threadIdx.x >> 6);
  if (node >= N) return;
  int lane = threadIdx.x & 63;
  int slot = lane >> 4;
  int c4 = (lane & 15) << 2;
  int beg = rowptr[node], end = rowptr[node + 1];
  float ax = 0.f, ay = 0.f, az = 0.f, aw = 0.f;
  int e = beg + slot;
  for (; e + 12 < end; e += 16) {
    int s0 = eidx[e], s1 = eidx[e + 4], s2 = eidx[e + 8], s3 = eidx[e + 12];
    float4 v0 = *(const float4*)(Z + (size_t)s0 * 64 + c4);
    float4 v1 = *(const float4*)(Z + (size_t)s1 * 64 + c4);
    float4 v2 = *(const float4*)(Z + (size_t)s2 * 64 + c4);
    float4 v3 = *(const float4*)(Z + (size_t)s3 * 64 + c4);
    ax += v0.x + v1.x + v2.x + v3.x;
    ay += v0.y + v1.y + v2.y + v3.y;
    az += v0.z + v1.z + v2.z + v3.z;
    aw += v0.w + v1.w + v2.w + v3.w;
  }
  for (; e < end; e += 4) {
    int s0 = eidx[e];
    float4 v0 = *(const float4*)(Z + (size_t)s0 * 64 + c4);
    ax += v0.x; ay += v0.y; az += v0.z; aw += v0.w;
  }
#pragma unroll
  for (int off = 16; off < 64; off <<= 1) {
    ax += __shfl_xor(ax, off);
    ay += __shfl_xor(ay, off);
    az += __shfl_xor(az, off);
    aw += __shfl_xor(aw, off);
  }
  if (slot == 0) {
    float4 self = *(const float4*)(Z + (size_t)node * 64 + c4);
    float4 o = make_float4(ax + self.x, ay + self.y, az + self.z, aw + self.w);
    *(float4*)(G + (size_t)node * 64 + c4) = o;
  }
}

// Final gather (4-deep ILP): writes packed split-bf16 (hi/lo) for the head.
__global__ __launch_bounds__(256) void gather64h(const int* __restrict__ rowptr,
                                                 const int* __restrict__ eidx,
                                                 const float* __restrict__ Z,
                                                 u16* __restrict__ Ghi,
                                                 u16* __restrict__ Glo, int N) {
  int node = blockIdx.x * 4 + (threadIdx.x >> 6);
  if (node >= N) return;
  int lane = threadIdx.x & 63;
  int slot = lane >> 4;
  int c4 = (lane & 15) << 2;
  int beg = rowptr[node], end = rowptr[node + 1];
  float ax = 0.f, ay = 0.f, az = 0.f, aw = 0.f;
  int e = beg + slot;
  for (; e + 12 < end; e += 16) {
    int s0 = eidx[e], s1 = eidx[e + 4], s2 = eidx[e + 8], s3 = eidx[e + 12];
    float4 v0 = *(const float4*)(Z + (size_t)s0 * 64 + c4);
    float4 v1 = *(const float4*)(Z + (size_t)s1 * 64 + c4);
    float4 v2 = *(const float4*)(Z + (size_t)s2 * 64 + c4);
    float4 v3 = *(const float4*)(Z + (size_t)s3 * 64 + c4);
    ax += v0.x + v1.x + v2.x + v3.x;
    ay += v0.y + v1.y + v2.y + v3.y;
    az += v0.z + v1.z + v2.z + v3.z;
    aw += v0.w + v1.w + v2.w + v3.w;
  }
  for (; e < end; e += 4) {
    int s0 = eidx[e];
    float4 v0 = *(const float4*)(Z + (size_t)s0 * 64 + c4);
    ax += v0.x; ay += v0.y; az += v0.z; aw += v0.w;
  }
#pragma unroll
  for (int off = 16; off < 64; off <<= 1) {
    ax += __shfl_xor(ax, off);
    ay += __shfl_xor(ay, off);
    az += __shfl_xor(az, off);
    aw += __shfl_xor(aw, off);
  }
  if (slot == 0) {
    float4 self = *(const float4*)(Z + (size_t)node * 64 + c4);
    float o0 = ax + self.x, o1 = ay + self.y, o2 = az + self.z, o3 = aw + self.w;
    unsigned h0 = bf16_rne(o0), h1 = bf16_rne(o1), h2 = bf16_rne(o2), h3 = bf16_rne(o3);
    unsigned l0 = bf16_rne(o0 - __uint_as_float(h0 << 16));
    unsigned l1 = bf16_rne(o1 - __uint_as_float(h1 << 16));
    unsigned l2 = bf16_rne(o2 - __uint_as_float(h2 << 16));
    unsigned l3 = bf16_rne(o3 - __uint_as_float(h3 << 16));
    uint2 hv = make_uint2(h0 | (h1 << 16), h2 | (h3 << 16));
    uint2 lv = make_uint2(l0 | (l1 << 16), l2 | (l3 << 16));
    *(uint2*)(Ghi + (size_t)node * 64 + c4) = hv;
    *(uint2*)(Glo + (size_t)node * 64 + c4) = lv;
  }
}

// Head weight prep: cx = sh@W, W' = sc[k]*W packed split-bf16 in fragment
// order (lane = ((k>>3)&3)*16 + col%16, j = k&7).
// Bh/Bl index: [(head*6+cc)][p=k>>5][ct][lane][j]. grid.x=12.
__global__ __launch_bounds__(256) void prep_head(
    const float* __restrict__ bns, const float* __restrict__ g,
    const float* __restrict__ be, const float* __restrict__ Wmu,
    const float* __restrict__ Wls, u16* __restrict__ Bh, u16* __restrict__ Bl,
    float* __restrict__ cmu, float* __restrict__ cls, float invN) {
  __shared__ float sc[64], sh[64], part[2][128];
  int t = threadIdx.x;
  if (t < 64) {
    float mean = bns[t] * invN;
    float var = bns[64 + t] * invN - mean * mean;
    float s = g[t] * rsqrtf(var + BN_EPS);
    sc[t] = s;
    sh[t] = be[t] - mean * s;
  }
  __syncthreads();
  int blk = blockIdx.x;
  int head = blk >= 6 ? 1 : 0;
  int cc = head ? blk - 6 : blk;
  int c0 = cc * 128;
  const float* W = head ? Wls : Wmu;
  float* cx = head ? cls : cmu;
  int cl = t & 127, kh = t >> 7;
  int c = c0 + cl;
  int ct = cl >> 4, jc = cl & 15;
  size_t base = (size_t)(head * 6 + cc) * 2 * 8 * 64 * 8;
  float p = 0.f;
  for (int k = kh * 32; k < kh * 32 + 32; ++k) {
    float w = W[(size_t)k * 768 + c];
    float wc = sc[k] * w;
    p += sh[k] * w;
    unsigned hi = bf16_rne(wc);
    unsigned lo = bf16_rne(wc - __uint_as_float(hi << 16));
    int lane = ((k >> 3) & 3) * 16 + jc;
    size_t idx = base + (((size_t)kh * 8 + ct) * 64 + lane) * 8 + (k & 7);
    Bh[idx] = (u16)hi;
    Bl[idx] = (u16)lo;
  }
  part[kh][cl] = p;
  __syncthreads();
  if (t < 128) cx[c0 + t] = part[0][t] + part[1][t];
}

// Layers 2/3 GEMM with integrated BN-weight prep: block computes sc/sh from
// prev-layer bns, stages raw W and scales in LDS, computes cx = sh@W.
// Z_next = LeakyReLU(dv*(G @ W') + dv*q[r]*cx + b) * dv, plus BN stats of o.
__global__ __launch_bounds__(256, 4) void gemm_bnq2(
    const float* __restrict__ G, const float* __restrict__ dinv,
    const float* __restrict__ q, const float* __restrict__ W,
    const float* __restrict__ g, const float* __restrict__ be,
    const float* __restrict__ bnsPrev, const float* __restrict__ b,
    float* __restrict__ Z, float* __restrict__ bnsOut, float invN, int N) {
  __shared__ __align__(16) float P[64][68];
  __shared__ __align__(16) float Ws[64][64];
  __shared__ float scl[64], shl[64], cxl[64], part[4][64];
  const int t = threadIdx.x;
  const int r0 = blockIdx.x * 64;

  if (t < 64) {
    float mean = bnsPrev[t] * invN;
    float var = bnsPrev[64 + t] * invN - mean * mean;
    float s = g[t] * rsqrtf(var + BN_EPS);
    scl[t] = s;
    shl[t] = be[t] - mean * s;
  }
  for (int i = t; i < 1024; i += 256) {
    int r = i >> 4, k4 = (i & 15) << 2, gr = r0 + r;
    float4 v = make_float4(0.f, 0.f, 0.f, 0.f);
    if (gr < N) v = *(const float4*)(G + (size_t)gr * 64 + k4);
    *(float4*)&P[r][k4] = v;
  }
  for (int i = t; i < 4096; i += 256) Ws[i >> 6][i & 63] = W[i];
  __syncthreads();

  {  // scale Ws by sc[k] and accumulate cx partials
    const int c = t & 63, k0 = t >> 6;
    float p = 0.f;
#pragma unroll
    for (int s = 0; s < 16; ++s) {
      int k = k0 + (s << 2);
      float w = Ws[k][c];
      Ws[k][c] = scl[k] * w;
      p += shl[k] * w;
    }
    part[k0][c] = p;
  }
  __syncthreads();
  if (t < 64) cxl[t] = part[0][t] + part[1][t] + part[2][t] + part[3][t];
  __syncthreads();

  const int tr = t >> 4, tc4 = (t & 15) << 2;
  float acc[4][4] = {};
#pragma unroll 8
  for (int k = 0; k < 64; ++k) {
    float4 w = *(const float4*)&Ws[k][tc4];
#pragma unroll
    for (int i = 0; i < 4; ++i) {
      float a = P[tr + 16 * i][k];
      acc[i][0] += a * w.x;
      acc[i][1] += a * w.y;
      acc[i][2] += a * w.z;
      acc[i][3] += a * w.w;
    }
  }

  float s1[4] = {0.f, 0.f, 0.f, 0.f}, s2[4] = {0.f, 0.f, 0.f, 0.f};
  float4 bb = *(const float4*)(b + tc4);
  float4 cc = make_float4(cxl[tc4], cxl[tc4 + 1], cxl[tc4 + 2], cxl[tc4 + 3]);
#pragma unroll
  for (int i = 0; i < 4; ++i) {
    int r = r0 + tr + 16 * i;
    if (r < N) {
      float dv = dinv[r];
      float dq = dv * q[r];
      float u0 = acc[i][0] * dv + dq * cc.x + bb.x;
      float u1 = acc[i][1] * dv + dq * cc.y + bb.y;
      float u2 = acc[i][2] * dv + dq * cc.z + bb.z;
      float u3 = acc[i][3] * dv + dq * cc.w + bb.w;
      float o0 = u0 >= 0.f ? u0 : NEG_SLOPE * u0;
      float o1 = u1 >= 0.f ? u1 : NEG_SLOPE * u1;
      float o2 = u2 >= 0.f ? u2 : NEG_SLOPE * u2;
      float o3 = u3 >= 0.f ? u3 : NEG_SLOPE * u3;
      float4 z = make_float4(o0 * dv, o1 * dv, o2 * dv, o3 * dv);
      *(float4*)(Z + (size_t)r * 64 + tc4) = z;
      s1[0] += o0; s2[0] += o0 * o0;
      s1[1] += o1; s2[1] += o1 * o1;
      s1[2] += o2; s2[2] += o2 * o2;
      s1[3] += o3; s2[3] += o3 * o3;
    }
  }
  __syncthreads();  // Ws no longer needed; reuse for BN reduction
  float (*red1)[64] = (float(*)[64]) & Ws[0][0];
  float (*red2)[64] = (float(*)[64]) & Ws[16][0];
#pragma unroll
  for (int j = 0; j < 4; ++j) {
    red1[tr][tc4 + j] = s1[j];
    red2[tr][tc4 + j] = s2[j];
  }
  __syncthreads();
  if (t < 64) {
    float a1 = 0.f, a2 = 0.f;
#pragma unroll
    for (int i = 0; i < 16; ++i) {
      a1 += red1[i][t];
      a2 += red2[i][t];
    }
    atomicAdd(&bnsOut[t], a1);
    atomicAdd(&bnsOut[64 + t], a2);
  }
}

// Weight-stationary MFMA head with LDS-staged coalesced stores (r18).
// Grid (64, 12): block owns one 128-col chunk, loads its 32 W-frags once,
// strides over 64-row tiles. Raw MFMA D (lane = 4 cols of one row) goes to
// per-wave LDS [16][132]; then 16 row-stores of 512B (64 lanes x float2)
// with the epilogue applied at store time.
__global__ __launch_bounds__(256) void head_mfma2(
    const u16* __restrict__ Ghi, const u16* __restrict__ Glo,
    const float* __restrict__ dinv, const float* __restrict__ q,
    const u16* __restrict__ Bh, const u16* __restrict__ Bl,
    const float* __restrict__ cmu, const float* __restrict__ bmu,
    const float* __restrict__ cls, const float* __restrict__ bls,
    float* __restrict__ OUT, int N, int ntiles) {
  __shared__ __align__(16) float tile[4][16][132];
  const int t = threadIdx.x;
  const int w = t >> 6, l = t & 63;
  const int yy = blockIdx.y;
  const int head = (yy >= 6) ? 1 : 0;
  const int cc = head ? yy - 6 : yy;
  const int c0 = cc * 128;
  const float* cx = head ? cls : cmu;
  const float* bb = head ? bls : bmu;
  float* O = OUT + (head ? (size_t)N * 768 : 0);

  const size_t base = (size_t)(head * 6 + cc) * 2 * 8 * 64 * 8;
  const u16* bhp = Bh + base;
  const u16* blp = Bl + base;
  bf16x8 wh[8][2], wl[8][2];
#pragma unroll
  for (int ct = 0; ct < 8; ++ct) {
    wh[ct][0] = *(const bf16x8*)(bhp + (((size_t)ct) * 64 + l) * 8);
    wh[ct][1] = *(const bf16x8*)(bhp + (((size_t)(8 + ct)) * 64 + l) * 8);
    wl[ct][0] = *(const bf16x8*)(blp + (((size_t)ct) * 64 + l) * 8);
    wl[ct][1] = *(const bf16x8*)(blp + (((size_t)(8 + ct)) * 64 + l) * 8);
  }

  // loop-invariant store-phase operands: lane covers cols c0 + l*2, l*2+1
  const float2 cxv = *(const float2*)(cx + c0 + l * 2);
  const float2 bbv = *(const float2*)(bb + c0 + l * 2);
  const int colq = (l >> 4) << 2;  // D col quartet within a 16-col tile

  for (int tl = blockIdx.x; tl < ntiles; tl += gridDim.x) {
    const int rowb = tl * 64 + w * 16;
    const int grow = rowb + (l & 15);
    const int gc = grow < N ? grow : N - 1;
    const u16* gh = Ghi + (size_t)gc * 64 + ((l >> 4) << 3);
    const u16* gl = Glo + (size_t)gc * 64 + ((l >> 4) << 3);
    const bf16x8 gh0 = *(const bf16x8*)gh;
    const bf16x8 gh1 = *(const bf16x8*)(gh + 32);
    const bf16x8 gl0 = *(const bf16x8*)gl;
    const bf16x8 gl1 = *(const bf16x8*)(gl + 32);

#pragma unroll
    for (int ct = 0; ct < 8; ++ct) {
      f32x4 a = {0.f, 0.f, 0.f, 0.f};
      a = __builtin_amdgcn_mfma_f32_16x16x32_bf16(wh[ct][0], gh0, a, 0, 0, 0);
      a = __builtin_amdgcn_mfma_f32_16x16x32_bf16(wh[ct][1], gh1, a, 0, 0, 0);
      a = __builtin_amdgcn_mfma_f32_16x16x32_bf16(wl[ct][0], gh0, a, 0, 0, 0);
      a = __builtin_amdgcn_mfma_f32_16x16x32_bf16(wl[ct][1], gh1, a, 0, 0, 0);
      a = __builtin_amdgcn_mfma_f32_16x16x32_bf16(wh[ct][0], gl0, a, 0, 0, 0);
      a = __builtin_amdgcn_mfma_f32_16x16x32_bf16(wh[ct][1], gl1, a, 0, 0, 0);
      *(f32x4*)&tile[w][l & 15][ct * 16 + colq] = a;  // raw; epilogue at store
    }
    // Per-wave LDS visibility only (lockstep wave64) — no block barrier.
#pragma unroll 4
    for (int r = 0; r < 16; ++r) {
      int row = rowb + r;
      if (row < N) {
        float dv = dinv[row];
        float dq = dv * q[row];
        float2 a = *(const float2*)&tile[w][r][l * 2];
        float2 o = make_float2(a.x * dv + dq * cxv.x + bbv.x,
                               a.y * dv + dq * cxv.y + bbv.y);
        *(float2*)(O + (size_t)row * 768 + c0 + l * 2) = o;
      }
    }
  }
}

extern "C" void kernel_launch(void* const* d_in, const int* in_sizes, int n_in,
                              void* d_out, int out_size, void* d_ws, size_t ws_size,
                              hipStream_t stream) {
  const float* x   = (const float*)d_in[0];
  const int*   ei  = (const int*)d_in[1];
  const float* W1  = (const float*)d_in[2];
  const float* b1  = (const float*)d_in[3];
  const float* g1  = (const float*)d_in[4];
  const float* be1 = (const float*)d_in[5];
  const float* W2  = (const float*)d_in[6];
  const float* b2  = (const float*)d_in[7];
  const float* g2  = (const float*)d_in[8];
  const float* be2 = (const float*)d_in[9];
  const float* W3  = (const float*)d_in[10];
  const float* b3  = (const float*)d_in[11];
  const float* g3  = (const float*)d_in[12];
  const float* be3 = (const float*)d_in[13];
  const float* Wmu = (const float*)d_in[14];
  const float* bmu = (const float*)d_in[15];
  const float* Wls = (const float*)d_in[16];
  const float* bls = (const float*)d_in[17];

  const int N = in_sizes[0] / 3;
  const int E = in_sizes[1] / 2;
  const int* src = ei;
  const int* dst = ei + E;
  float* out = (float*)d_out;

  char* ws = (char*)d_ws;
  size_t o = 0;
  float* dinv = (float*)(ws + o); o += (size_t)N * 4;
  float* qv   = (float*)(ws + o); o += (size_t)N * 4;
  float* bns  = (float*)(ws + o); o += 384 * 4;
  float4* xd  = (float4*)(ws + o); o += (size_t)N * 16;
  u16* Bh     = (u16*)(ws + o);   o += (size_t)12 * 2 * 8 * 64 * 8 * 2;
  u16* Bl     = (u16*)(ws + o);   o += (size_t)12 * 2 * 8 * 64 * 8 * 2;
  float* cmu  = (float*)(ws + o); o += 768 * 4;
  float* cls  = (float*)(ws + o); o += 768 * 4;
  u16* Ghi    = (u16*)(ws + o);   o += (size_t)N * 64 * 2;
  u16* Glo    = (u16*)(ws + o);   o += (size_t)N * 64 * 2;
  int* cnt    = (int*)(ws + o);   o += (size_t)N * 4;
  int* rowptr = (int*)(ws + o);   o += ((size_t)N + 1) * 4;
  int* cursor = (int*)(ws + o);   o += (size_t)N * 4;
  int* bsum   = (int*)(ws + o);   o += 64 * 4;
  int* eidx   = (int*)(ws + o);   o += (size_t)E * 4;
  float* B0   = (float*)(ws + o); o += (size_t)N * 64 * 4;
  float* B1   = (float*)(ws + o); o += (size_t)N * 64 * 4;
  // ws_size observed ~1.2 GB; total used ~46 MB.

  const float invN = 1.0f / (float)N;
  int nbN = (N + 255) / 256;
  int nbE = (E + 255) / 256;
  int gb  = (N + 63) / 64;
  int wb  = (N + 3) / 4;
  int sbA = (N + 1023) / 1024;

  // CSR build (edge_index constant across all 4 propagations)
  init_k<<<nbN, 256, 0, stream>>>(cnt, bns, N);
  hist_k<<<nbE, 256, 0, stream>>>(dst, cnt, E);
  scanA<<<sbA, 1024, 0, stream>>>(cnt, rowptr, bsum, N);
  scanB<<<1, 64, 0, stream>>>(bsum, sbA);
  scanC<<<nbN, 256, 0, stream>>>(cnt, rowptr, cursor, bsum, x, dinv, xd, N, E);
  fill_k<<<nbE, 256, 0, stream>>>(src, dst, cursor, eidx, E);

  // ---- layer 1: fused gather(xd float4)+GEMM+stats, writes Z1=B0 and q ----
  l1_fused<<<1024, 256, 0, stream>>>(rowptr, eidx, xd, W1, b1, B0, qv, bns, N);

  // ---- layer 2 (split gather -> GEMM w/ integrated prep) ----
  gather64<<<wb, 256, 0, stream>>>(rowptr, eidx, B0, B1, N);      // B1 = G1
  gemm_bnq2<<<gb, 256, 0, stream>>>(B1, dinv, qv, W2, g1, be1, bns + 0, b2,
                                    B0, bns + 128, invN, N);

  // ---- layer 3 ----
  gather64<<<wb, 256, 0, stream>>>(rowptr, eidx, B0, B1, N);      // B1 = G2
  gemm_bnq2<<<gb, 256, 0, stream>>>(B1, dinv, qv, W3, g2, be2, bns + 128, b3,
                                    B0, bns + 256, invN, N);
  prep_head<<<12, 256, 0, stream>>>(bns + 256, g3, be3, Wmu, Wls, Bh, Bl, cmu, cls, invN);

  // ---- final propagate (split-bf16 output) + weight-stationary MFMA head ----
  gather64h<<<wb, 256, 0, stream>>>(rowptr, eidx, B0, Ghi, Glo, N);
  dim3 hgrid(64, 12);
  head_mfma2<<<hgrid, 256, 0, stream>>>(Ghi, Glo, dinv, qv, Bh, Bl,
                                        cmu, bmu, cls, bls, out, N, gb);
}

// Round 23
// 407.787 us; speedup vs baseline: 1.0496x; 1.0496x over previous
//
#include <hip/hip_runtime.h>
#include <cstddef>

// GCN encoder, BN-folded, split gather->GEMM (fusion net-negative r10/r11).
// Head: weight-stationary split-bf16 MFMA, direct stores (LDS staging r19
// regressed +12us: store rows already get 64B-contiguous per instruction).
// r20: head grid.x 64->192 for more latency-hiding TLP (W-frags replicated,
// reload is L2-resident).
// prop(h)[d] = dinv[d]*(P(h)[d] @ W) + b; BN folded via W'=diag(sc)W, c'=sh@W,
// q[d] = sum dinv; epilogue u = dv*acc + dv*q[r]*c'[c] + b[c].

#define NEG_SLOPE 0.01f
#define BN_EPS 1e-5f

typedef unsigned short u16;
typedef __attribute__((ext_vector_type(8))) short bf16x8;
typedef __attribute__((ext_vector_type(4))) float f32x4;

__device__ __forceinline__ unsigned bf16_rne(float x) {
  unsigned u = __float_as_uint(x);
  return (u + 0x7fffu + ((u >> 16) & 1u)) >> 16;
}

__global__ __launch_bounds__(256) void init_k(int* __restrict__ cnt,
                                              float* __restrict__ bns, int N) {
  int i = blockIdx.x * 256 + threadIdx.x;
  if (i < N) cnt[i] = 0;
  if (i < 384) bns[i] = 0.0f;  // 3 layers x {sum[64], sumsq[64]}
}

__global__ __launch_bounds__(256) void hist_k(const int* __restrict__ dst,
                                              int* __restrict__ cnt, int E) {
  int e = blockIdx.x * 256 + threadIdx.x;
  if (e < E) atomicAdd(&cnt[dst[e]], 1);
}

__global__ __launch_bounds__(1024) void scanA(const int* __restrict__ cnt,
                                              int* __restrict__ pre,
                                              int* __restrict__ bsum, int N) {
  __shared__ int sh[1024];
  const int t = threadIdx.x;
  const int i = blockIdx.x * 1024 + t;
  int c = (i < N) ? cnt[i] : 0;
  sh[t] = c;
  __syncthreads();
  for (int off = 1; off < 1024; off <<= 1) {
    int v = (t >= off) ? sh[t - off] : 0;
    __syncthreads();
    sh[t] += v;
    __syncthreads();
  }
  if (i < N) pre[i] = sh[t] - c;  // exclusive
  if (t == 1023) bsum[blockIdx.x] = sh[t];
}

__global__ __launch_bounds__(64) void scanB(int* __restrict__ bsum, int nb) {
  int t = threadIdx.x;
  int orig = (t < nb) ? bsum[t] : 0;
  int v = orig;
#pragma unroll
  for (int off = 1; off < 64; off <<= 1) {
    int u = __shfl_up(v, off);
    if (t >= off) v += u;
  }
  if (t < nb) bsum[t] = v - orig;
}

// Phase C: rowptr/cursor finalize, dinv, and xd = {x*dinv, dinv} pack.
__global__ __launch_bounds__(256) void scanC(const int* __restrict__ cnt,
                                             int* __restrict__ rowptr,
                                             int* __restrict__ cursor,
                                             const int* __restrict__ bsum,
                                             const float* __restrict__ x,
                                             float* __restrict__ dinv,
                                             float4* __restrict__ xd,
                                             int N, int E) {
  int i = blockIdx.x * 256 + threadIdx.x;
  if (i < N) {
    int rp = rowptr[i] + bsum[i >> 10];
    rowptr[i] = rp;
    cursor[i] = rp;
    float dv = rsqrtf((float)(cnt[i] + 1));  // +1 self loop
    dinv[i] = dv;
    xd[i] = make_float4(x[i * 3] * dv, x[i * 3 + 1] * dv, x[i * 3 + 2] * dv, dv);
  }
  if (i == 0) rowptr[N] = E;
}

__global__ __launch_bounds__(256) void fill_k(const int* __restrict__ src,
                                              const int* __restrict__ dst,
                                              int* __restrict__ cursor,
                                              int* __restrict__ eidx, int E) {
  int e = blockIdx.x * 256 + threadIdx.x;
  if (e >= E) return;
  int p = atomicAdd(&cursor[dst[e]], 1);
  eidx[p] = src[e];
}

// Layer 1 fully fused (3ch gather via xd float4 + 3->64 matvec + stats + q).
__global__ __launch_bounds__(256) void l1_fused(
    const int* __restrict__ rowptr, const int* __restrict__ eidx,
    const float4* __restrict__ xd, const float* __restrict__ W1,
    const float* __restrict__ b1, float* __restrict__ Z, float* __restrict__ q,
    float* __restrict__ bns, int N) {
  const int t = threadIdx.x, lane = t & 63, wid = t >> 6;
  const int gw = blockIdx.x * 4 + wid;
  const int nw = gridDim.x * 4;
  const float w0 = W1[lane], w1 = W1[64 + lane], w2 = W1[128 + lane];
  const float bb = b1[lane];
  float s1 = 0.f, s2 = 0.f;
  for (int node = gw; node < N; node += nw) {
    int beg = rowptr[node], end = rowptr[node + 1];
    float a0 = 0.f, a1 = 0.f, a2 = 0.f, aq = 0.f;
    for (int e = beg + lane; e < end; e += 64) {
      float4 v = xd[eidx[e]];
      a0 += v.x;
      a1 += v.y;
      a2 += v.z;
      aq += v.w;
    }
#pragma unroll
    for (int off = 32; off; off >>= 1) {
      a0 += __shfl_xor(a0, off);
      a1 += __shfl_xor(a1, off);
      a2 += __shfl_xor(a2, off);
      aq += __shfl_xor(aq, off);
    }
    float4 sv = xd[node];
    float dv = sv.w;
    a0 += sv.x;
    a1 += sv.y;
    a2 += sv.z;
    aq += dv;
    float u = dv * (a0 * w0 + a1 * w1 + a2 * w2) + bb;
    float o = u >= 0.f ? u : NEG_SLOPE * u;
    Z[(size_t)node * 64 + lane] = o * dv;
    s1 += o;
    s2 += o * o;
    if (lane == 0) q[node] = aq;
  }
  __shared__ float red[8][64];
  red[wid][lane] = s1;
  red[4 + wid][lane] = s2;
  __syncthreads();
  if (t < 64) {
    atomicAdd(&bns[t], red[0][t] + red[1][t] + red[2][t] + red[3][t]);
    atomicAdd(&bns[64 + t], red[4][t] + red[5][t] + red[6][t] + red[7][t]);
  }
}

// Standalone gather, 4-deep ILP: G[node][c] = Z[node][c] + sum Z[src][c].
__global__ __launch_bounds__(256) void gather64(const int* __restrict__ rowptr,
                                                const int* __restrict__ eidx,
                                                const float* __restrict__ Z,
                                                float* __restrict__ G, int N) {
  int node = blockIdx.x * 4 + (threadIdx.x >> 6);
  if (node >= N) return;
  int lane = threadIdx.x & 63;
  int slot = lane >> 4;
  int c4 = (lane & 15) << 2;
  int beg = rowptr[node], end = rowptr[node + 1];
  float ax = 0.f, ay = 0.f, az = 0.f, aw = 0.f;
  int e = beg + slot;
  for (; e + 12 < end; e += 16) {
    int s0 = eidx[e], s1 = eidx[e + 4], s2 = eidx[e + 8], s3 = eidx[e + 12];
    float4 v0 = *(const float4*)(Z + (size_t)s0 * 64 + c4);
    float4 v1 = *(const float4*)(Z + (size_t)s1 * 64 + c4);
    float4 v2 = *(const float4*)(Z + (size_t)s2 * 64 + c4);
    float4 v3 = *(const float4*)(Z + (size_t)s3 * 64 + c4);
    ax += v0.x + v1.x + v2.x + v3.x;
    ay += v0.y + v1.y + v2.y + v3.y;
    az += v0.z + v1.z + v2.z + v3.z;
    aw += v0.w + v1.w + v2.w + v3.w;
  }
  for (; e < end; e += 4) {
    int s0 = eidx[e];
    float4 v0 = *(const float4*)(Z + (size_t)s0 * 64 + c4);
    ax += v0.x; ay += v0.y; az += v0.z; aw += v0.w;
  }
#pragma unroll
  for (int off = 16; off < 64; off <<= 1) {
    ax += __shfl_xor(ax, off);
    ay += __shfl_xor(ay, off);
    az += __shfl_xor(az, off);
    aw += __shfl_xor(aw, off);
  }
  if (slot == 0) {
    float4 self = *(const float4*)(Z + (size_t)node * 64 + c4);
    float4 o = make_float4(ax + self.x, ay + self.y, az + self.z, aw + self.w);
    *(float4*)(G + (size_t)node * 64 + c4) = o;
  }
}

// Final gather (4-deep ILP): writes packed split-bf16 (hi/lo) for the head.
__global__ __launch_bounds__(256) void gather64h(const int* __restrict__ rowptr,
                                                 const int* __restrict__ eidx,
                                                 const float* __restrict__ Z,
                                                 u16* __restrict__ Ghi,
                                                 u16* __restrict__ Glo, int N) {
  int node = blockIdx.x * 4 + (threadIdx.x >> 6);
  if (node >= N) return;
  int lane = threadIdx.x & 63;
  int slot = lane >> 4;
  int c4 = (lane & 15) << 2;
  int beg = rowptr[node], end = rowptr[node + 1];
  float ax = 0.f, ay = 0.f, az = 0.f, aw = 0.f;
  int e = beg + slot;
  for (; e + 12 < end; e += 16) {
    int s0 = eidx[e], s1 = eidx[e + 4], s2 = eidx[e + 8], s3 = eidx[e + 12];
    float4 v0 = *(const float4*)(Z + (size_t)s0 * 64 + c4);
    float4 v1 = *(const float4*)(Z + (size_t)s1 * 64 + c4);
    float4 v2 = *(const float4*)(Z + (size_t)s2 * 64 + c4);
    float4 v3 = *(const float4*)(Z + (size_t)s3 * 64 + c4);
    ax += v0.x + v1.x + v2.x + v3.x;
    ay += v0.y + v1.y + v2.y + v3.y;
    az += v0.z + v1.z + v2.z + v3.z;
    aw += v0.w + v1.w + v2.w + v3.w;
  }
  for (; e < end; e += 4) {
    int s0 = eidx[e];
    float4 v0 = *(const float4*)(Z + (size_t)s0 * 64 + c4);
    ax += v0.x; ay += v0.y; az += v0.z; aw += v0.w;
  }
#pragma unroll
  for (int off = 16; off < 64; off <<= 1) {
    ax += __shfl_xor(ax, off);
    ay += __shfl_xor(ay, off);
    az += __shfl_xor(az, off);
    aw += __shfl_xor(aw, off);
  }
  if (slot == 0) {
    float4 self = *(const float4*)(Z + (size_t)node * 64 + c4);
    float o0 = ax + self.x, o1 = ay + self.y, o2 = az + self.z, o3 = aw + self.w;
    unsigned h0 = bf16_rne(o0), h1 = bf16_rne(o1), h2 = bf16_rne(o2), h3 = bf16_rne(o3);
    unsigned l0 = bf16_rne(o0 - __uint_as_float(h0 << 16));
    unsigned l1 = bf16_rne(o1 - __uint_as_float(h1 << 16));
    unsigned l2 = bf16_rne(o2 - __uint_as_float(h2 << 16));
    unsigned l3 = bf16_rne(o3 - __uint_as_float(h3 << 16));
    uint2 hv = make_uint2(h0 | (h1 << 16), h2 | (h3 << 16));
    uint2 lv = make_uint2(l0 | (l1 << 16), l2 | (l3 << 16));
    *(uint2*)(Ghi + (size_t)node * 64 + c4) = hv;
    *(uint2*)(Glo + (size_t)node * 64 + c4) = lv;
  }
}

// Head weight prep: cx = sh@W, W' = sc[k]*W packed split-bf16 in fragment
// order (lane = ((k>>3)&3)*16 + col%16, j = k&7).
// Bh/Bl index: [(head*6+cc)][p=k>>5][ct][lane][j]. grid.x=12.
__global__ __launch_bounds__(256) void prep_head(
    const float* __restrict__ bns, const float* __restrict__ g,
    const float* __restrict__ be, const float* __restrict__ Wmu,
    const float* __restrict__ Wls, u16* __restrict__ Bh, u16* __restrict__ Bl,
    float* __restrict__ cmu, float* __restrict__ cls, float invN) {
  __shared__ float sc[64], sh[64], part[2][128];
  int t = threadIdx.x;
  if (t < 64) {
    float mean = bns[t] * invN;
    float var = bns[64 + t] * invN - mean * mean;
    float s = g[t] * rsqrtf(var + BN_EPS);
    sc[t] = s;
    sh[t] = be[t] - mean * s;
  }
  __syncthreads();
  int blk = blockIdx.x;
  int head = blk >= 6 ? 1 : 0;
  int cc = head ? blk - 6 : blk;
  int c0 = cc * 128;
  const float* W = head ? Wls : Wmu;
  float* cx = head ? cls : cmu;
  int cl = t & 127, kh = t >> 7;
  int c = c0 + cl;
  int ct = cl >> 4, jc = cl & 15;
  size_t base = (size_t)(head * 6 + cc) * 2 * 8 * 64 * 8;
  float p = 0.f;
  for (int k = kh * 32; k < kh * 32 + 32; ++k) {
    float w = W[(size_t)k * 768 + c];
    float wc = sc[k] * w;
    p += sh[k] * w;
    unsigned hi = bf16_rne(wc);
    unsigned lo = bf16_rne(wc - __uint_as_float(hi << 16));
    int lane = ((k >> 3) & 3) * 16 + jc;
    size_t idx = base + (((size_t)kh * 8 + ct) * 64 + lane) * 8 + (k & 7);
    Bh[idx] = (u16)hi;
    Bl[idx] = (u16)lo;
  }
  part[kh][cl] = p;
  __syncthreads();
  if (t < 128) cx[c0 + t] = part[0][t] + part[1][t];
}

// Layers 2/3 GEMM with integrated BN-weight prep: block computes sc/sh from
// prev-layer bns, stages raw W and scales in LDS, computes cx = sh@W.
// Z_next = LeakyReLU(dv*(G @ W') + dv*q[r]*cx + b) * dv, plus BN stats of o.
__global__ __launch_bounds__(256, 4) void gemm_bnq2(
    const float* __restrict__ G, const float* __restrict__ dinv,
    const float* __restrict__ q, const float* __restrict__ W,
    const float* __restrict__ g, const float* __restrict__ be,
    const float* __restrict__ bnsPrev, const float* __restrict__ b,
    float* __restrict__ Z, float* __restrict__ bnsOut, float invN, int N) {
  __shared__ __align__(16) float P[64][68];
  __shared__ __align__(16) float Ws[64][64];
  __shared__ float scl[64], shl[64], cxl[64], part[4][64];
  const int t = threadIdx.x;
  const int r0 = blockIdx.x * 64;

  if (t < 64) {
    float mean = bnsPrev[t] * invN;
    float var = bnsPrev[64 + t] * invN - mean * mean;
    float s = g[t] * rsqrtf(var + BN_EPS);
    scl[t] = s;
    shl[t] = be[t] - mean * s;
  }
  for (int i = t; i < 1024; i += 256) {
    int r = i >> 4, k4 = (i & 15) << 2, gr = r0 + r;
    float4 v = make_float4(0.f, 0.f, 0.f, 0.f);
    if (gr < N) v = *(const float4*)(G + (size_t)gr * 64 + k4);
    *(float4*)&P[r][k4] = v;
  }
  for (int i = t; i < 4096; i += 256) Ws[i >> 6][i & 63] = W[i];
  __syncthreads();

  {  // scale Ws by sc[k] and accumulate cx partials
    const int c = t & 63, k0 = t >> 6;
    float p = 0.f;
#pragma unroll
    for (int s = 0; s < 16; ++s) {
      int k = k0 + (s << 2);
      float w = Ws[k][c];
      Ws[k][c] = scl[k] * w;
      p += shl[k] * w;
    }
    part[k0][c] = p;
  }
  __syncthreads();
  if (t < 64) cxl[t] = part[0][t] + part[1][t] + part[2][t] + part[3][t];
  __syncthreads();

  const int tr = t >> 4, tc4 = (t & 15) << 2;
  float acc[4][4] = {};
#pragma unroll 8
  for (int k = 0; k < 64; ++k) {
    float4 w = *(const float4*)&Ws[k][tc4];
#pragma unroll
    for (int i = 0; i < 4; ++i) {
      float a = P[tr + 16 * i][k];
      acc[i][0] += a * w.x;
      acc[i][1] += a * w.y;
      acc[i][2] += a * w.z;
      acc[i][3] += a * w.w;
    }
  }

  float s1[4] = {0.f, 0.f, 0.f, 0.f}, s2[4] = {0.f, 0.f, 0.f, 0.f};
  float4 bb = *(const float4*)(b + tc4);
  float4 cc = make_float4(cxl[tc4], cxl[tc4 + 1], cxl[tc4 + 2], cxl[tc4 + 3]);
#pragma unroll
  for (int i = 0; i < 4; ++i) {
    int r = r0 + tr + 16 * i;
    if (r < N) {
      float dv = dinv[r];
      float dq = dv * q[r];
      float u0 = acc[i][0] * dv + dq * cc.x + bb.x;
      float u1 = acc[i][1] * dv + dq * cc.y + bb.y;
      float u2 = acc[i][2] * dv + dq * cc.z + bb.z;
      float u3 = acc[i][3] * dv + dq * cc.w + bb.w;
      float o0 = u0 >= 0.f ? u0 : NEG_SLOPE * u0;
      float o1 = u1 >= 0.f ? u1 : NEG_SLOPE * u1;
      float o2 = u2 >= 0.f ? u2 : NEG_SLOPE * u2;
      float o3 = u3 >= 0.f ? u3 : NEG_SLOPE * u3;
      float4 z = make_float4(o0 * dv, o1 * dv, o2 * dv, o3 * dv);
      *(float4*)(Z + (size_t)r * 64 + tc4) = z;
      s1[0] += o0; s2[0] += o0 * o0;
      s1[1] += o1; s2[1] += o1 * o1;
      s1[2] += o2; s2[2] += o2 * o2;
      s1[3] += o3; s2[3] += o3 * o3;
    }
  }
  __syncthreads();  // Ws no longer needed; reuse for BN reduction
  float (*red1)[64] = (float(*)[64]) & Ws[0][0];
  float (*red2)[64] = (float(*)[64]) & Ws[16][0];
#pragma unroll
  for (int j = 0; j < 4; ++j) {
    red1[tr][tc4 + j] = s1[j];
    red2[tr][tc4 + j] = s2[j];
  }
  __syncthreads();
  if (t < 64) {
    float a1 = 0.f, a2 = 0.f;
#pragma unroll
    for (int i = 0; i < 16; ++i) {
      a1 += red1[i][t];
      a2 += red2[i][t];
    }
    atomicAdd(&bnsOut[t], a1);
    atomicAdd(&bnsOut[64 + t], a2);
  }
}

// Weight-stationary MFMA head (r17 form, direct stores). Grid (192, 12):
// block owns one 128-col chunk, loads its 32 W-frags once, strides over
// 64-row tiles. mfma(W, G) -> lane holds 4 consecutive cols of one row;
// lanes l, l+16, l+32, l+48 share a row -> 64B/row per store instruction.
__global__ __launch_bounds__(256) void head_mfma2(
    const u16* __restrict__ Ghi, const u16* __restrict__ Glo,
    const float* __restrict__ dinv, const float* __restrict__ q,
    const u16* __restrict__ Bh, const u16* __restrict__ Bl,
    const float* __restrict__ cmu, const float* __restrict__ bmu,
    const float* __restrict__ cls, const float* __restrict__ bls,
    float* __restrict__ OUT, int N, int ntiles) {
  const int t = threadIdx.x;
  const int w = t >> 6, l = t & 63;
  const int yy = blockIdx.y;
  const int head = (yy >= 6) ? 1 : 0;
  const int cc = head ? yy - 6 : yy;
  const int c0 = cc * 128;
  const float* cx = head ? cls : cmu;
  const float* bb = head ? bls : bmu;
  float* O = OUT + (head ? (size_t)N * 768 : 0);

  const size_t base = (size_t)(head * 6 + cc) * 2 * 8 * 64 * 8;
  const u16* bhp = Bh + base;
  const u16* blp = Bl + base;
  bf16x8 wh[8][2], wl[8][2];
#pragma unroll
  for (int ct = 0; ct < 8; ++ct) {
    wh[ct][0] = *(const bf16x8*)(bhp + (((size_t)ct) * 64 + l) * 8);
    wh[ct][1] = *(const bf16x8*)(bhp + (((size_t)(8 + ct)) * 64 + l) * 8);
    wl[ct][0] = *(const bf16x8*)(blp + (((size_t)ct) * 64 + l) * 8);
    wl[ct][1] = *(const bf16x8*)(blp + (((size_t)(8 + ct)) * 64 + l) * 8);
  }

  const int colb = c0 + ((l >> 4) << 2);
  for (int tile = blockIdx.x; tile < ntiles; tile += gridDim.x) {
    const int grow = tile * 64 + w * 16 + (l & 15);
    const int gc = grow < N ? grow : N - 1;
    const u16* gh = Ghi + (size_t)gc * 64 + ((l >> 4) << 3);
    const u16* gl = Glo + (size_t)gc * 64 + ((l >> 4) << 3);
    const bf16x8 gh0 = *(const bf16x8*)gh;
    const bf16x8 gh1 = *(const bf16x8*)(gh + 32);
    const bf16x8 gl0 = *(const bf16x8*)gl;
    const bf16x8 gl1 = *(const bf16x8*)(gl + 32);
    const float dv = dinv[gc];
    const float dq = dv * q[gc];

#pragma unroll
    for (int ct = 0; ct < 8; ++ct) {
      f32x4 a = {0.f, 0.f, 0.f, 0.f};
      a = __builtin_amdgcn_mfma_f32_16x16x32_bf16(wh[ct][0], gh0, a, 0, 0, 0);
      a = __builtin_amdgcn_mfma_f32_16x16x32_bf16(wh[ct][1], gh1, a, 0, 0, 0);
      a = __builtin_amdgcn_mfma_f32_16x16x32_bf16(wl[ct][0], gh0, a, 0, 0, 0);
      a = __builtin_amdgcn_mfma_f32_16x16x32_bf16(wl[ct][1], gh1, a, 0, 0, 0);
      a = __builtin_amdgcn_mfma_f32_16x16x32_bf16(wh[ct][0], gl0, a, 0, 0, 0);
      a = __builtin_amdgcn_mfma_f32_16x16x32_bf16(wh[ct][1], gl1, a, 0, 0, 0);
      if (grow < N) {
        int col = colb + ct * 16;
        float4 cxv = *(const float4*)(cx + col);
        float4 bbv = *(const float4*)(bb + col);
        float4 o = make_float4(a[0] * dv + dq * cxv.x + bbv.x,
                               a[1] * dv + dq * cxv.y + bbv.y,
                               a[2] * dv + dq * cxv.z + bbv.z,
                               a[3] * dv + dq * cxv.w + bbv.w);
        *(float4*)(O + (size_t)grow * 768 + col) = o;
      }
    }
  }
}

extern "C" void kernel_launch(void* const* d_in, const int* in_sizes, int n_in,
                              void* d_out, int out_size, void* d_ws, size_t ws_size,
                              hipStream_t stream) {
  const float* x   = (const float*)d_in[0];
  const int*   ei  = (const int*)d_in[1];
  const float* W1  = (const float*)d_in[2];
  const float* b1  = (const float*)d_in[3];
  const float* g1  = (const float*)d_in[4];
  const float* be1 = (const float*)d_in[5];
  const float* W2  = (const float*)d_in[6];
  const float* b2  = (const float*)d_in[7];
  const float* g2  = (const float*)d_in[8];
  const float* be2 = (const float*)d_in[9];
  const float* W3  = (const float*)d_in[10];
  const float* b3  = (const float*)d_in[11];
  const float* g3  = (const float*)d_in[12];
  const float* be3 = (const float*)d_in[13];
  const float* Wmu = (const float*)d_in[14];
  const float* bmu = (const float*)d_in[15];
  const float* Wls = (const float*)d_in[16];
  const float* bls = (const float*)d_in[17];

  const int N = in_sizes[0] / 3;
  const int E = in_sizes[1] / 2;
  const int* src = ei;
  const int* dst = ei + E;
  float* out = (float*)d_out;

  char* ws = (char*)d_ws;
  size_t o = 0;
  float* dinv = (float*)(ws + o); o += (size_t)N * 4;
  float* qv   = (float*)(ws + o); o += (size_t)N * 4;
  float* bns  = (float*)(ws + o); o += 384 * 4;
  float4* xd  = (float4*)(ws + o); o += (size_t)N * 16;
  u16* Bh     = (u16*)(ws + o);   o += (size_t)12 * 2 * 8 * 64 * 8 * 2;
  u16* Bl     = (u16*)(ws + o);   o += (size_t)12 * 2 * 8 * 64 * 8 * 2;
  float* cmu  = (float*)(ws + o); o += 768 * 4;
  float* cls  = (float*)(ws + o); o += 768 * 4;
  u16* Ghi    = (u16*)(ws + o);   o += (size_t)N * 64 * 2;
  u16* Glo    = (u16*)(ws + o);   o += (size_t)N * 64 * 2;
  int* cnt    = (int*)(ws + o);   o += (size_t)N * 4;
  int* rowptr = (int*)(ws + o);   o += ((size_t)N + 1) * 4;
  int* cursor = (int*)(ws + o);   o += (size_t)N * 4;
  int* bsum   = (int*)(ws + o);   o += 64 * 4;
  int* eidx   = (int*)(ws + o);   o += (size_t)E * 4;
  float* B0   = (float*)(ws + o); o += (size_t)N * 64 * 4;
  float* B1   = (float*)(ws + o); o += (size_t)N * 64 * 4;
  // ws_size observed ~1.2 GB; total used ~46 MB.

  const float invN = 1.0f / (float)N;
  int nbN = (N + 255) / 256;
  int nbE = (E + 255) / 256;
  int gb  = (N + 63) / 64;
  int wb  = (N + 3) / 4;
  int sbA = (N + 1023) / 1024;

  // CSR build (edge_index constant across all 4 propagations)
  init_k<<<nbN, 256, 0, stream>>>(cnt, bns, N);
  hist_k<<<nbE, 256, 0, stream>>>(dst, cnt, E);
  scanA<<<sbA, 1024, 0, stream>>>(cnt, rowptr, bsum, N);
  scanB<<<1, 64, 0, stream>>>(bsum, sbA);
  scanC<<<nbN, 256, 0, stream>>>(cnt, rowptr, cursor, bsum, x, dinv, xd, N, E);
  fill_k<<<nbE, 256, 0, stream>>>(src, dst, cursor, eidx, E);

  // ---- layer 1: fused gather(xd float4)+GEMM+stats, writes Z1=B0 and q ----
  l1_fused<<<1024, 256, 0, stream>>>(rowptr, eidx, xd, W1, b1, B0, qv, bns, N);

  // ---- layer 2 (split gather -> GEMM w/ integrated prep) ----
  gather64<<<wb, 256, 0, stream>>>(rowptr, eidx, B0, B1, N);      // B1 = G1
  gemm_bnq2<<<gb, 256, 0, stream>>>(B1, dinv, qv, W2, g1, be1, bns + 0, b2,
                                    B0, bns + 128, invN, N);

  // ---- layer 3 ----
  gather64<<<wb, 256, 0, stream>>>(rowptr, eidx, B0, B1, N);      // B1 = G2
  gemm_bnq2<<<gb, 256, 0, stream>>>(B1, dinv, qv, W3, g2, be2, bns + 128, b3,
                                    B0, bns + 256, invN, N);
  prep_head<<<12, 256, 0, stream>>>(bns + 256, g3, be3, Wmu, Wls, Bh, Bl, cmu, cls, invN);

  // ---- final propagate (split-bf16 output) + weight-stationary MFMA head ----
  gather64h<<<wb, 256, 0, stream>>>(rowptr, eidx, B0, Ghi, Glo, N);
  dim3 hgrid(192, 12);
  head_mfma2<<<hgrid, 256, 0, stream>>>(Ghi, Glo, dinv, qv, Bh, Bl,
                                        cmu, bmu, cls, bls, out, N, gb);
}

// Round 24
// 372.247 us; speedup vs baseline: 1.1498x; 1.0955x over previous
//
#include <hip/hip_runtime.h>
#include <cstddef>

// GCN encoder, BN-folded, split gather->GEMM. Head: weight-stationary
// split-bf16 MFMA, direct stores, grid (192,12) (r23 best = 407.8us).
// r24: Z propagation buffers stored as plain bf16 (rows 128B) — halves the
// random-read traffic of all three gathers (the dominant remaining cost).
// Gather sums accumulate in fp32; BN renormalizes each layer so the one
// bf16 rounding per layer does not compound.
// prop(h)[d] = dinv[d]*(P(h)[d] @ W) + b; BN folded via W'=diag(sc)W, c'=sh@W,
// q[d] = sum dinv; epilogue u = dv*acc + dv*q[r]*c'[c] + b[c].

#define NEG_SLOPE 0.01f
#define BN_EPS 1e-5f

typedef unsigned short u16;
typedef __attribute__((ext_vector_type(8))) short bf16x8;
typedef __attribute__((ext_vector_type(4))) float f32x4;

__device__ __forceinline__ unsigned bf16_rne(float x) {
  unsigned u = __float_as_uint(x);
  return (u + 0x7fffu + ((u >> 16) & 1u)) >> 16;
}
__device__ __forceinline__ float blo(unsigned u) { return __uint_as_float(u << 16); }
__device__ __forceinline__ float bhi(unsigned u) { return __uint_as_float(u & 0xffff0000u); }

__global__ __launch_bounds__(256) void init_k(int* __restrict__ cnt,
                                              float* __restrict__ bns, int N) {
  int i = blockIdx.x * 256 + threadIdx.x;
  if (i < N) cnt[i] = 0;
  if (i < 384) bns[i] = 0.0f;  // 3 layers x {sum[64], sumsq[64]}
}

__global__ __launch_bounds__(256) void hist_k(const int* __restrict__ dst,
                                              int* __restrict__ cnt, int E) {
  int e = blockIdx.x * 256 + threadIdx.x;
  if (e < E) atomicAdd(&cnt[dst[e]], 1);
}

__global__ __launch_bounds__(1024) void scanA(const int* __restrict__ cnt,
                                              int* __restrict__ pre,
                                              int* __restrict__ bsum, int N) {
  __shared__ int sh[1024];
  const int t = threadIdx.x;
  const int i = blockIdx.x * 1024 + t;
  int c = (i < N) ? cnt[i] : 0;
  sh[t] = c;
  __syncthreads();
  for (int off = 1; off < 1024; off <<= 1) {
    int v = (t >= off) ? sh[t - off] : 0;
    __syncthreads();
    sh[t] += v;
    __syncthreads();
  }
  if (i < N) pre[i] = sh[t] - c;  // exclusive
  if (t == 1023) bsum[blockIdx.x] = sh[t];
}

__global__ __launch_bounds__(64) void scanB(int* __restrict__ bsum, int nb) {
  int t = threadIdx.x;
  int orig = (t < nb) ? bsum[t] : 0;
  int v = orig;
#pragma unroll
  for (int off = 1; off < 64; off <<= 1) {
    int u = __shfl_up(v, off);
    if (t >= off) v += u;
  }
  if (t < nb) bsum[t] = v - orig;
}

// Phase C: rowptr/cursor finalize, dinv, and xd = {x*dinv, dinv} pack.
__global__ __launch_bounds__(256) void scanC(const int* __restrict__ cnt,
                                             int* __restrict__ rowptr,
                                             int* __restrict__ cursor,
                                             const int* __restrict__ bsum,
                                             const float* __restrict__ x,
                                             float* __restrict__ dinv,
                                             float4* __restrict__ xd,
                                             int N, int E) {
  int i = blockIdx.x * 256 + threadIdx.x;
  if (i < N) {
    int rp = rowptr[i] + bsum[i >> 10];
    rowptr[i] = rp;
    cursor[i] = rp;
    float dv = rsqrtf((float)(cnt[i] + 1));  // +1 self loop
    dinv[i] = dv;
    xd[i] = make_float4(x[i * 3] * dv, x[i * 3 + 1] * dv, x[i * 3 + 2] * dv, dv);
  }
  if (i == 0) rowptr[N] = E;
}

__global__ __launch_bounds__(256) void fill_k(const int* __restrict__ src,
                                              const int* __restrict__ dst,
                                              int* __restrict__ cursor,
                                              int* __restrict__ eidx, int E) {
  int e = blockIdx.x * 256 + threadIdx.x;
  if (e >= E) return;
  int p = atomicAdd(&cursor[dst[e]], 1);
  eidx[p] = src[e];
}

// Layer 1 fully fused (3ch gather via xd float4 + 3->64 matvec + stats + q).
// Z written as bf16 (lane = channel -> 128B contiguous per node).
__global__ __launch_bounds__(256) void l1_fused(
    const int* __restrict__ rowptr, const int* __restrict__ eidx,
    const float4* __restrict__ xd, const float* __restrict__ W1,
    const float* __restrict__ b1, u16* __restrict__ Zb, float* __restrict__ q,
    float* __restrict__ bns, int N) {
  const int t = threadIdx.x, lane = t & 63, wid = t >> 6;
  const int gw = blockIdx.x * 4 + wid;
  const int nw = gridDim.x * 4;
  const float w0 = W1[lane], w1 = W1[64 + lane], w2 = W1[128 + lane];
  const float bb = b1[lane];
  float s1 = 0.f, s2 = 0.f;
  for (int node = gw; node < N; node += nw) {
    int beg = rowptr[node], end = rowptr[node + 1];
    float a0 = 0.f, a1 = 0.f, a2 = 0.f, aq = 0.f;
    for (int e = beg + lane; e < end; e += 64) {
      float4 v = xd[eidx[e]];
      a0 += v.x;
      a1 += v.y;
      a2 += v.z;
      aq += v.w;
    }
#pragma unroll
    for (int off = 32; off; off >>= 1) {
      a0 += __shfl_xor(a0, off);
      a1 += __shfl_xor(a1, off);
      a2 += __shfl_xor(a2, off);
      aq += __shfl_xor(aq, off);
    }
    float4 sv = xd[node];
    float dv = sv.w;
    a0 += sv.x;
    a1 += sv.y;
    a2 += sv.z;
    aq += dv;
    float u = dv * (a0 * w0 + a1 * w1 + a2 * w2) + bb;
    float o = u >= 0.f ? u : NEG_SLOPE * u;
    Zb[(size_t)node * 64 + lane] = (u16)bf16_rne(o * dv);
    s1 += o;
    s2 += o * o;
    if (lane == 0) q[node] = aq;
  }
  __shared__ float red[8][64];
  red[wid][lane] = s1;
  red[4 + wid][lane] = s2;
  __syncthreads();
  if (t < 64) {
    atomicAdd(&bns[t], red[0][t] + red[1][t] + red[2][t] + red[3][t]);
    atomicAdd(&bns[64 + t], red[4][t] + red[5][t] + red[6][t] + red[7][t]);
  }
}

// Gather from bf16 Z, fp32 accumulate, fp32 G out. One wave/node;
// lane = (slot: lane>>4) x (4 ch: (lane&15)*4); slot issues 4 independent
// 8B loads (e, e+4, e+8, e+12) -> 16 edges/iter/wave.
__global__ __launch_bounds__(256) void gather64(const int* __restrict__ rowptr,
                                                const int* __restrict__ eidx,
                                                const u16* __restrict__ Zb,
                                                float* __restrict__ G, int N) {
  int node = blockIdx.x * 4 + (threadIdx.x >> 6);
  if (node >= N) return;
  int lane = threadIdx.x & 63;
  int slot = lane >> 4;
  int c4 = (lane & 15) << 2;
  int beg = rowptr[node], end = rowptr[node + 1];
  float ax = 0.f, ay = 0.f, az = 0.f, aw = 0.f;
  int e = beg + slot;
  for (; e + 12 < end; e += 16) {
    int s0 = eidx[e], s1 = eidx[e + 4], s2 = eidx[e + 8], s3 = eidx[e + 12];
    uint2 v0 = *(const uint2*)(Zb + (size_t)s0 * 64 + c4);
    uint2 v1 = *(const uint2*)(Zb + (size_t)s1 * 64 + c4);
    uint2 v2 = *(const uint2*)(Zb + (size_t)s2 * 64 + c4);
    uint2 v3 = *(const uint2*)(Zb + (size_t)s3 * 64 + c4);
    ax += blo(v0.x) + blo(v1.x) + blo(v2.x) + blo(v3.x);
    ay += bhi(v0.x) + bhi(v1.x) + bhi(v2.x) + bhi(v3.x);
    az += blo(v0.y) + blo(v1.y) + blo(v2.y) + blo(v3.y);
    aw += bhi(v0.y) + bhi(v1.y) + bhi(v2.y) + bhi(v3.y);
  }
  for (; e < end; e += 4) {
    uint2 v0 = *(const uint2*)(Zb + (size_t)eidx[e] * 64 + c4);
    ax += blo(v0.x); ay += bhi(v0.x); az += blo(v0.y); aw += bhi(v0.y);
  }
#pragma unroll
  for (int off = 16; off < 64; off <<= 1) {
    ax += __shfl_xor(ax, off);
    ay += __shfl_xor(ay, off);
    az += __shfl_xor(az, off);
    aw += __shfl_xor(aw, off);
  }
  if (slot == 0) {
    uint2 sv = *(const uint2*)(Zb + (size_t)node * 64 + c4);
    float4 o = make_float4(ax + blo(sv.x), ay + bhi(sv.x),
                           az + blo(sv.y), aw + bhi(sv.y));
    *(float4*)(G + (size_t)node * 64 + c4) = o;
  }
}

// Final gather from bf16 Z: fp32 sums -> packed split-bf16 (hi/lo) for head.
__global__ __launch_bounds__(256) void gather64h(const int* __restrict__ rowptr,
                                                 const int* __restrict__ eidx,
                                                 const u16* __restrict__ Zb,
                                                 u16* __restrict__ Ghi,
                                                 u16* __restrict__ Glo, int N) {
  int node = blockIdx.x * 4 + (threadIdx.x >> 6);
  if (node >= N) return;
  int lane = threadIdx.x & 63;
  int slot = lane >> 4;
  int c4 = (lane & 15) << 2;
  int beg = rowptr[node], end = rowptr[node + 1];
  float ax = 0.f, ay = 0.f, az = 0.f, aw = 0.f;
  int e = beg + slot;
  for (; e + 12 < end; e += 16) {
    int s0 = eidx[e], s1 = eidx[e + 4], s2 = eidx[e + 8], s3 = eidx[e + 12];
    uint2 v0 = *(const uint2*)(Zb + (size_t)s0 * 64 + c4);
    uint2 v1 = *(const uint2*)(Zb + (size_t)s1 * 64 + c4);
    uint2 v2 = *(const uint2*)(Zb + (size_t)s2 * 64 + c4);
    uint2 v3 = *(const uint2*)(Zb + (size_t)s3 * 64 + c4);
    ax += blo(v0.x) + blo(v1.x) + blo(v2.x) + blo(v3.x);
    ay += bhi(v0.x) + bhi(v1.x) + bhi(v2.x) + bhi(v3.x);
    az += blo(v0.y) + blo(v1.y) + blo(v2.y) + blo(v3.y);
    aw += bhi(v0.y) + bhi(v1.y) + bhi(v2.y) + bhi(v3.y);
  }
  for (; e < end; e += 4) {
    uint2 v0 = *(const uint2*)(Zb + (size_t)eidx[e] * 64 + c4);
    ax += blo(v0.x); ay += bhi(v0.x); az += blo(v0.y); aw += bhi(v0.y);
  }
#pragma unroll
  for (int off = 16; off < 64; off <<= 1) {
    ax += __shfl_xor(ax, off);
    ay += __shfl_xor(ay, off);
    az += __shfl_xor(az, off);
    aw += __shfl_xor(aw, off);
  }
  if (slot == 0) {
    uint2 sv = *(const uint2*)(Zb + (size_t)node * 64 + c4);
    float o0 = ax + blo(sv.x), o1 = ay + bhi(sv.x);
    float o2 = az + blo(sv.y), o3 = aw + bhi(sv.y);
    unsigned h0 = bf16_rne(o0), h1 = bf16_rne(o1), h2 = bf16_rne(o2), h3 = bf16_rne(o3);
    unsigned l0 = bf16_rne(o0 - __uint_as_float(h0 << 16));
    unsigned l1 = bf16_rne(o1 - __uint_as_float(h1 << 16));
    unsigned l2 = bf16_rne(o2 - __uint_as_float(h2 << 16));
    unsigned l3 = bf16_rne(o3 - __uint_as_float(h3 << 16));
    uint2 hv = make_uint2(h0 | (h1 << 16), h2 | (h3 << 16));
    uint2 lv = make_uint2(l0 | (l1 << 16), l2 | (l3 << 16));
    *(uint2*)(Ghi + (size_t)node * 64 + c4) = hv;
    *(uint2*)(Glo + (size_t)node * 64 + c4) = lv;
  }
}

// Head weight prep: cx = sh@W, W' = sc[k]*W packed split-bf16 in fragment
// order (lane = ((k>>3)&3)*16 + col%16, j = k&7).
// Bh/Bl index: [(head*6+cc)][p=k>>5][ct][lane][j]. grid.x=12.
__global__ __launch_bounds__(256) void prep_head(
    const float* __restrict__ bns, const float* __restrict__ g,
    const float* __restrict__ be, const float* __restrict__ Wmu,
    const float* __restrict__ Wls, u16* __restrict__ Bh, u16* __restrict__ Bl,
    float* __restrict__ cmu, float* __restrict__ cls, float invN) {
  __shared__ float sc[64], sh[64], part[2][128];
  int t = threadIdx.x;
  if (t < 64) {
    float mean = bns[t] * invN;
    float var = bns[64 + t] * invN - mean * mean;
    float s = g[t] * rsqrtf(var + BN_EPS);
    sc[t] = s;
    sh[t] = be[t] - mean * s;
  }
  __syncthreads();
  int blk = blockIdx.x;
  int head = blk >= 6 ? 1 : 0;
  int cc = head ? blk - 6 : blk;
  int c0 = cc * 128;
  const float* W = head ? Wls : Wmu;
  float* cx = head ? cls : cmu;
  int cl = t & 127, kh = t >> 7;
  int c = c0 + cl;
  int ct = cl >> 4, jc = cl & 15;
  size_t base = (size_t)(head * 6 + cc) * 2 * 8 * 64 * 8;
  float p = 0.f;
  for (int k = kh * 32; k < kh * 32 + 32; ++k) {
    float w = W[(size_t)k * 768 + c];
    float wc = sc[k] * w;
    p += sh[k] * w;
    unsigned hi = bf16_rne(wc);
    unsigned lo = bf16_rne(wc - __uint_as_float(hi << 16));
    int lane = ((k >> 3) & 3) * 16 + jc;
    size_t idx = base + (((size_t)kh * 8 + ct) * 64 + lane) * 8 + (k & 7);
    Bh[idx] = (u16)hi;
    Bl[idx] = (u16)lo;
  }
  part[kh][cl] = p;
  __syncthreads();
  if (t < 128) cx[c0 + t] = part[0][t] + part[1][t];
}

// Layers 2/3 GEMM with integrated BN-weight prep: fp32 G in, bf16 Z out.
// Z_next = LeakyReLU(dv*(G @ W') + dv*q[r]*cx + b) * dv, plus BN stats of o.
__global__ __launch_bounds__(256, 4) void gemm_bnq2(
    const float* __restrict__ G, const float* __restrict__ dinv,
    const float* __restrict__ q, const float* __restrict__ W,
    const float* __restrict__ g, const float* __restrict__ be,
    const float* __restrict__ bnsPrev, const float* __restrict__ b,
    u16* __restrict__ Zb, float* __restrict__ bnsOut, float invN, int N) {
  __shared__ __align__(16) float P[64][68];
  __shared__ __align__(16) float Ws[64][64];
  __shared__ float scl[64], shl[64], cxl[64], part[4][64];
  const int t = threadIdx.x;
  const int r0 = blockIdx.x * 64;

  if (t < 64) {
    float mean = bnsPrev[t] * invN;
    float var = bnsPrev[64 + t] * invN - mean * mean;
    float s = g[t] * rsqrtf(var + BN_EPS);
    scl[t] = s;
    shl[t] = be[t] - mean * s;
  }
  for (int i = t; i < 1024; i += 256) {
    int r = i >> 4, k4 = (i & 15) << 2, gr = r0 + r;
    float4 v = make_float4(0.f, 0.f, 0.f, 0.f);
    if (gr < N) v = *(const float4*)(G + (size_t)gr * 64 + k4);
    *(float4*)&P[r][k4] = v;
  }
  for (int i = t; i < 4096; i += 256) Ws[i >> 6][i & 63] = W[i];
  __syncthreads();

  {  // scale Ws by sc[k] and accumulate cx partials
    const int c = t & 63, k0 = t >> 6;
    float p = 0.f;
#pragma unroll
    for (int s = 0; s < 16; ++s) {
      int k = k0 + (s << 2);
      float w = Ws[k][c];
      Ws[k][c] = scl[k] * w;
      p += shl[k] * w;
    }
    part[k0][c] = p;
  }
  __syncthreads();
  if (t < 64) cxl[t] = part[0][t] + part[1][t] + part[2][t] + part[3][t];
  __syncthreads();

  const int tr = t >> 4, tc4 = (t & 15) << 2;
  float acc[4][4] = {};
#pragma unroll 8
  for (int k = 0; k < 64; ++k) {
    float4 w = *(const float4*)&Ws[k][tc4];
#pragma unroll
    for (int i = 0; i < 4; ++i) {
      float a = P[tr + 16 * i][k];
      acc[i][0] += a * w.x;
      acc[i][1] += a * w.y;
      acc[i][2] += a * w.z;
      acc[i][3] += a * w.w;
    }
  }

  float s1[4] = {0.f, 0.f, 0.f, 0.f}, s2[4] = {0.f, 0.f, 0.f, 0.f};
  float4 bb = *(const float4*)(b + tc4);
  float4 cc = make_float4(cxl[tc4], cxl[tc4 + 1], cxl[tc4 + 2], cxl[tc4 + 3]);
#pragma unroll
  for (int i = 0; i < 4; ++i) {
    int r = r0 + tr + 16 * i;
    if (r < N) {
      float dv = dinv[r];
      float dq = dv * q[r];
      float u0 = acc[i][0] * dv + dq * cc.x + bb.x;
      float u1 = acc[i][1] * dv + dq * cc.y + bb.y;
      float u2 = acc[i][2] * dv + dq * cc.z + bb.z;
      float u3 = acc[i][3] * dv + dq * cc.w + bb.w;
      float o0 = u0 >= 0.f ? u0 : NEG_SLOPE * u0;
      float o1 = u1 >= 0.f ? u1 : NEG_SLOPE * u1;
      float o2 = u2 >= 0.f ? u2 : NEG_SLOPE * u2;
      float o3 = u3 >= 0.f ? u3 : NEG_SLOPE * u3;
      unsigned p0 = bf16_rne(o0 * dv) | (bf16_rne(o1 * dv) << 16);
      unsigned p1 = bf16_rne(o2 * dv) | (bf16_rne(o3 * dv) << 16);
      *(uint2*)(Zb + (size_t)r * 64 + tc4) = make_uint2(p0, p1);
      s1[0] += o0; s2[0] += o0 * o0;
      s1[1] += o1; s2[1] += o1 * o1;
      s1[2] += o2; s2[2] += o2 * o2;
      s1[3] += o3; s2[3] += o3 * o3;
    }
  }
  __syncthreads();  // Ws no longer needed; reuse for BN reduction
  float (*red1)[64] = (float(*)[64]) & Ws[0][0];
  float (*red2)[64] = (float(*)[64]) & Ws[16][0];
#pragma unroll
  for (int j = 0; j < 4; ++j) {
    red1[tr][tc4 + j] = s1[j];
    red2[tr][tc4 + j] = s2[j];
  }
  __syncthreads();
  if (t < 64) {
    float a1 = 0.f, a2 = 0.f;
#pragma unroll
    for (int i = 0; i < 16; ++i) {
      a1 += red1[i][t];
      a2 += red2[i][t];
    }
    atomicAdd(&bnsOut[t], a1);
    atomicAdd(&bnsOut[64 + t], a2);
  }
}

// Weight-stationary MFMA head (direct stores). Grid (192, 12): block owns
// one 128-col chunk, loads its 32 W-frags once, strides over 64-row tiles.
__global__ __launch_bounds__(256) void head_mfma2(
    const u16* __restrict__ Ghi, const u16* __restrict__ Glo,
    const float* __restrict__ dinv, const float* __restrict__ q,
    const u16* __restrict__ Bh, const u16* __restrict__ Bl,
    const float* __restrict__ cmu, const float* __restrict__ bmu,
    const float* __restrict__ cls, const float* __restrict__ bls,
    float* __restrict__ OUT, int N, int ntiles) {
  const int t = threadIdx.x;
  const int w = t >> 6, l = t & 63;
  const int yy = blockIdx.y;
  const int head = (yy >= 6) ? 1 : 0;
  const int cc = head ? yy - 6 : yy;
  const int c0 = cc * 128;
  const float* cx = head ? cls : cmu;
  const float* bb = head ? bls : bmu;
  float* O = OUT + (head ? (size_t)N * 768 : 0);

  const size_t base = (size_t)(head * 6 + cc) * 2 * 8 * 64 * 8;
  const u16* bhp = Bh + base;
  const u16* blp = Bl + base;
  bf16x8 wh[8][2], wl[8][2];
#pragma unroll
  for (int ct = 0; ct < 8; ++ct) {
    wh[ct][0] = *(const bf16x8*)(bhp + (((size_t)ct) * 64 + l) * 8);
    wh[ct][1] = *(const bf16x8*)(bhp + (((size_t)(8 + ct)) * 64 + l) * 8);
    wl[ct][0] = *(const bf16x8*)(blp + (((size_t)ct) * 64 + l) * 8);
    wl[ct][1] = *(const bf16x8*)(blp + (((size_t)(8 + ct)) * 64 + l) * 8);
  }

  const int colb = c0 + ((l >> 4) << 2);
  for (int tile = blockIdx.x; tile < ntiles; tile += gridDim.x) {
    const int grow = tile * 64 + w * 16 + (l & 15);
    const int gc = grow < N ? grow : N - 1;
    const u16* gh = Ghi + (size_t)gc * 64 + ((l >> 4) << 3);
    const u16* gl = Glo + (size_t)gc * 64 + ((l >> 4) << 3);
    const bf16x8 gh0 = *(const bf16x8*)gh;
    const bf16x8 gh1 = *(const bf16x8*)(gh + 32);
    const bf16x8 gl0 = *(const bf16x8*)gl;
    const bf16x8 gl1 = *(const bf16x8*)(gl + 32);
    const float dv = dinv[gc];
    const float dq = dv * q[gc];

#pragma unroll
    for (int ct = 0; ct < 8; ++ct) {
      f32x4 a = {0.f, 0.f, 0.f, 0.f};
      a = __builtin_amdgcn_mfma_f32_16x16x32_bf16(wh[ct][0], gh0, a, 0, 0, 0);
      a = __builtin_amdgcn_mfma_f32_16x16x32_bf16(wh[ct][1], gh1, a, 0, 0, 0);
      a = __builtin_amdgcn_mfma_f32_16x16x32_bf16(wl[ct][0], gh0, a, 0, 0, 0);
      a = __builtin_amdgcn_mfma_f32_16x16x32_bf16(wl[ct][1], gh1, a, 0, 0, 0);
      a = __builtin_amdgcn_mfma_f32_16x16x32_bf16(wh[ct][0], gl0, a, 0, 0, 0);
      a = __builtin_amdgcn_mfma_f32_16x16x32_bf16(wh[ct][1], gl1, a, 0, 0, 0);
      if (grow < N) {
        int col = colb + ct * 16;
        float4 cxv = *(const float4*)(cx + col);
        float4 bbv = *(const float4*)(bb + col);
        float4 o = make_float4(a[0] * dv + dq * cxv.x + bbv.x,
                               a[1] * dv + dq * cxv.y + bbv.y,
                               a[2] * dv + dq * cxv.z + bbv.z,
                               a[3] * dv + dq * cxv.w + bbv.w);
        *(float4*)(O + (size_t)grow * 768 + col) = o;
      }
    }
  }
}

extern "C" void kernel_launch(void* const* d_in, const int* in_sizes, int n_in,
                              void* d_out, int out_size, void* d_ws, size_t ws_size,
                              hipStream_t stream) {
  const float* x   = (const float*)d_in[0];
  const int*   ei  = (const int*)d_in[1];
  const float* W1  = (const float*)d_in[2];
  const float* b1  = (const float*)d_in[3];
  const float* g1  = (const float*)d_in[4];
  const float* be1 = (const float*)d_in[5];
  const float* W2  = (const float*)d_in[6];
  const float* b2  = (const float*)d_in[7];
  const float* g2  = (const float*)d_in[8];
  const float* be2 = (const float*)d_in[9];
  const float* W3  = (const float*)d_in[10];
  const float* b3  = (const float*)d_in[11];
  const float* g3  = (const float*)d_in[12];
  const float* be3 = (const float*)d_in[13];
  const float* Wmu = (const float*)d_in[14];
  const float* bmu = (const float*)d_in[15];
  const float* Wls = (const float*)d_in[16];
  const float* bls = (const float*)d_in[17];

  const int N = in_sizes[0] / 3;
  const int E = in_sizes[1] / 2;
  const int* src = ei;
  const int* dst = ei + E;
  float* out = (float*)d_out;

  char* ws = (char*)d_ws;
  size_t o = 0;
  float* dinv = (float*)(ws + o); o += (size_t)N * 4;
  float* qv   = (float*)(ws + o); o += (size_t)N * 4;
  float* bns  = (float*)(ws + o); o += 384 * 4;
  float4* xd  = (float4*)(ws + o); o += (size_t)N * 16;
  u16* Bh     = (u16*)(ws + o);   o += (size_t)12 * 2 * 8 * 64 * 8 * 2;
  u16* Bl     = (u16*)(ws + o);   o += (size_t)12 * 2 * 8 * 64 * 8 * 2;
  float* cmu  = (float*)(ws + o); o += 768 * 4;
  float* cls  = (float*)(ws + o); o += 768 * 4;
  u16* Ghi    = (u16*)(ws + o);   o += (size_t)N * 64 * 2;
  u16* Glo    = (u16*)(ws + o);   o += (size_t)N * 64 * 2;
  u16* Zb     = (u16*)(ws + o);   o += (size_t)N * 64 * 2;
  float* Gf   = (float*)(ws + o); o += (size_t)N * 64 * 4;
  int* cnt    = (int*)(ws + o);   o += (size_t)N * 4;
  int* rowptr = (int*)(ws + o);   o += ((size_t)N + 1) * 4;
  int* cursor = (int*)(ws + o);   o += (size_t)N * 4;
  int* bsum   = (int*)(ws + o);   o += 64 * 4;
  int* eidx   = (int*)(ws + o);   o += (size_t)E * 4;
  // ws_size observed ~1.2 GB; total used ~33 MB.

  const float invN = 1.0f / (float)N;
  int nbN = (N + 255) / 256;
  int nbE = (E + 255) / 256;
  int gb  = (N + 63) / 64;
  int wb  = (N + 3) / 4;
  int sbA = (N + 1023) / 1024;

  // CSR build (edge_index constant across all 4 propagations)
  init_k<<<nbN, 256, 0, stream>>>(cnt, bns, N);
  hist_k<<<nbE, 256, 0, stream>>>(dst, cnt, E);
  scanA<<<sbA, 1024, 0, stream>>>(cnt, rowptr, bsum, N);
  scanB<<<1, 64, 0, stream>>>(bsum, sbA);
  scanC<<<nbN, 256, 0, stream>>>(cnt, rowptr, cursor, bsum, x, dinv, xd, N, E);
  fill_k<<<nbE, 256, 0, stream>>>(src, dst, cursor, eidx, E);

  // ---- layer 1: fused gather(xd float4)+GEMM+stats, writes Zb (bf16) + q ----
  l1_fused<<<1024, 256, 0, stream>>>(rowptr, eidx, xd, W1, b1, Zb, qv, bns, N);

  // ---- layer 2: gather(Zb bf16) -> Gf fp32 -> GEMM -> Zb bf16 ----
  gather64<<<wb, 256, 0, stream>>>(rowptr, eidx, Zb, Gf, N);
  gemm_bnq2<<<gb, 256, 0, stream>>>(Gf, dinv, qv, W2, g1, be1, bns + 0, b2,
                                    Zb, bns + 128, invN, N);

  // ---- layer 3 ----
  gather64<<<wb, 256, 0, stream>>>(rowptr, eidx, Zb, Gf, N);
  gemm_bnq2<<<gb, 256, 0, stream>>>(Gf, dinv, qv, W3, g2, be2, bns + 128, b3,
                                    Zb, bns + 256, invN, N);
  prep_head<<<12, 256, 0, stream>>>(bns + 256, g3, be3, Wmu, Wls, Bh, Bl, cmu, cls, invN);

  // ---- final propagate (split-bf16 out) + weight-stationary MFMA head ----
  gather64h<<<wb, 256, 0, stream>>>(rowptr, eidx, Zb, Ghi, Glo, N);
  dim3 hgrid(192, 12);
  head_mfma2<<<hgrid, 256, 0, stream>>>(Ghi, Glo, dinv, qv, Bh, Bl,
                                        cmu, bmu, cls, bls, out, N, gb);
}